// Round 1
// baseline (6086.803 us; speedup 1.0000x reference)
//
#include <hip/hip_runtime.h>

// GWNet on MI355X — round 0: correct fp32 baseline.
// Structure: CSR-spmm (Chebyshev terms) + flash-style fused attention
// (Az@Xt with per-column softmax stats precomputed) + per-batch head GEMM.
// Attention never materializes the 8192x8192 matrix -> ws need ~103 MB.
// Next rounds: bf16 MFMA for the fused attention (dominant cost).

#define NN 8192
#define NNZE 131072

typedef float4 f4;

// ---------------- CSR build ----------------
__global__ __launch_bounds__(256) void k_count(const int* __restrict__ idx, int* __restrict__ cnt){
  int e = blockIdx.x*256 + threadIdx.x;
  if (e < NNZE) atomicAdd(&cnt[idx[e]], 1);
}

__global__ __launch_bounds__(1024) void k_scan(const int* __restrict__ cnt, int* __restrict__ ptr){
  __shared__ int sums[1024];
  int t = threadIdx.x;
  int loc[8]; int s = 0;
  #pragma unroll
  for (int i=0;i<8;i++){ loc[i]=s; s += cnt[t*8+i]; }
  sums[t]=s; __syncthreads();
  for (int off=1; off<1024; off<<=1){
    int v = (t>=off) ? sums[t-off] : 0;
    __syncthreads();
    sums[t] += v;
    __syncthreads();
  }
  int excl = sums[t]-s;
  #pragma unroll
  for (int i=0;i<8;i++) ptr[t*8+i] = excl + loc[i];
  if (t==1023) ptr[NN] = sums[1023];
}

__global__ __launch_bounds__(256) void k_fill(const int* __restrict__ idx, const float* __restrict__ vals,
                                              int* __restrict__ cur, int* __restrict__ cidx, float* __restrict__ cval){
  int e = blockIdx.x*256 + threadIdx.x;
  if (e < NNZE){
    int r = idx[e], c = idx[NNZE+e];
    int p = atomicAdd(&cur[r], 1);
    cidx[p] = c; cval[p] = vals[e];
  }
}

// ---------------- transpose X (R, NN) -> (NN, R) ----------------
template<int R>
__global__ __launch_bounds__(256) void k_transpose(const float* __restrict__ src, float* __restrict__ dst){
  __shared__ float tile[32][33];
  int tx = threadIdx.x & 31, ty = threadIdx.x >> 5;
  int j0 = blockIdx.x*32, f0 = blockIdx.y*32;
  #pragma unroll
  for (int u=0;u<32;u+=8) tile[ty+u][tx] = src[(size_t)(f0+ty+u)*NN + j0+tx];
  __syncthreads();
  #pragma unroll
  for (int u=0;u<32;u+=8) dst[(size_t)(j0+ty+u)*R + f0+tx] = tile[tx][ty+u];
}

// ---------------- softmax column stats: m[j] = max_i relu(zi.zj), s[j] = sum exp(.-m) ----------------
__global__ __launch_bounds__(128) void k_colmax(const f4* __restrict__ Z4, float* __restrict__ mb){
  __shared__ f4 zi[64*16];
  int t = threadIdx.x;
  int j = blockIdx.x*128 + t;
  int i0 = blockIdx.y*1024;
  f4 zj[16];
  #pragma unroll
  for (int q=0;q<16;q++) zj[q] = Z4[(size_t)j*16+q];
  float mx = 0.f;  // relu lower bound
  for (int it=0; it<1024; it+=64){
    __syncthreads();
    #pragma unroll
    for (int u=0;u<8;u++){ int li=u*128+t; zi[li] = Z4[(size_t)(i0+it)*16 + li]; }
    __syncthreads();
    for (int i=0;i<64;i++){
      float d=0.f;
      #pragma unroll
      for (int q=0;q<16;q++){ f4 a=zi[i*16+q], b=zj[q]; d += a.x*b.x+a.y*b.y+a.z*b.z+a.w*b.w; }
      mx = fmaxf(mx, d);
    }
  }
  atomicMax((int*)(mb+j), __float_as_int(mx)); // valid: non-negative floats
}

__global__ __launch_bounds__(128) void k_colsum(const f4* __restrict__ Z4, const float* __restrict__ mb, float* __restrict__ sb){
  __shared__ f4 zi[64*16];
  int t = threadIdx.x;
  int j = blockIdx.x*128 + t;
  int i0 = blockIdx.y*1024;
  f4 zj[16];
  #pragma unroll
  for (int q=0;q<16;q++) zj[q] = Z4[(size_t)j*16+q];
  float mj = mb[j];
  float sm = 0.f;
  for (int it=0; it<1024; it+=64){
    __syncthreads();
    #pragma unroll
    for (int u=0;u<8;u++){ int li=u*128+t; zi[li] = Z4[(size_t)(i0+it)*16 + li]; }
    __syncthreads();
    for (int i=0;i<64;i++){
      float d=0.f;
      #pragma unroll
      for (int q=0;q<16;q++){ f4 a=zi[i*16+q], b=zj[q]; d += a.x*b.x+a.y*b.y+a.z*b.z+a.w*b.w; }
      sm += __expf(fmaxf(d,0.f) - mj);
    }
  }
  atomicAdd(sb+j, sm);
}

__global__ __launch_bounds__(256) void k_recip(float* s){
  int i = blockIdx.x*256 + threadIdx.x;
  if (i < NN) s[i] = 1.0f/s[i];
}

// ---------------- CSR spmm: out[r,:] (= or +=) ALPHA * sum_e v * in[c,:] ----------------
template<int F, int ALPHA, bool ACC>
__global__ __launch_bounds__(256) void k_spmm(const int* __restrict__ ptr, const int* __restrict__ cidx,
                                              const float* __restrict__ cval, const float* __restrict__ in,
                                              float* __restrict__ out){
  int r = blockIdx.x, t = threadIdx.x;
  int p0 = ptr[r], p1 = ptr[r+1];
  constexpr int PER = F/256;
  float acc[PER];
  #pragma unroll
  for (int u=0;u<PER;u++) acc[u]=0.f;
  for (int p=p0;p<p1;p++){
    int c = cidx[p]; float v = cval[p];
    #pragma unroll
    for (int u=0;u<PER;u++) acc[u] += v * in[(size_t)c*F + u*256 + t];
  }
  #pragma unroll
  for (int u=0;u<PER;u++){
    size_t o = (size_t)r*F + u*256 + t;
    float x = (float)ALPHA * acc[u];
    out[o] = ACC ? (out[o] + x) : x;
  }
}

// ---------------- elementwise ----------------
__global__ __launch_bounds__(256) void k_sub(const f4* __restrict__ a, const f4* __restrict__ b, f4* __restrict__ o, int n4){
  for (int i = blockIdx.x*256 + threadIdx.x; i < n4; i += gridDim.x*256){
    f4 x=a[i], y=b[i]; f4 r;
    r.x=x.x-y.x; r.y=x.y-y.y; r.z=x.z-y.z; r.w=x.w-y.w;
    o[i]=r;
  }
}
__global__ __launch_bounds__(256) void k_add(const f4* __restrict__ a, f4* __restrict__ o, int n4){
  for (int i = blockIdx.x*256 + threadIdx.x; i < n4; i += gridDim.x*256){
    f4 x=a[i], r=o[i];
    r.x+=x.x; r.y+=x.y; r.z+=x.z; r.w+=x.w;
    o[i]=r;
  }
}

// ---------------- fused attention: T += E @ (Y * sinv), E[i,k]=exp(relu(zi.zk)-m[k]) ----------------
// BM=32, BN=256, BK=32, 256 threads, 32 f32 acc/thread.
template<int F>
__global__ __launch_bounds__(256) void k_attn(const f4* __restrict__ Z4, const float* __restrict__ Y,
                                              const float* __restrict__ mb, const float* __restrict__ sinv,
                                              float* __restrict__ T){
  __shared__ f4 zi[32*16];
  __shared__ f4 zk[32*16];       // XOR-swizzled: row kk, q stored at q^(kk&7)
  __shared__ f4 yt[32*64];       // [kk][64 f4]
  __shared__ float stf[32*36];   // S^T: [kk][m], stride 36 for aligned f4 reads
  __shared__ float mk[32];
  int t = threadIdx.x;
  int m0 = blockIdx.x*32, n0 = blockIdx.y*256;
  #pragma unroll
  for (int u=0;u<2;u++){ int li=u*256+t; zi[li] = Z4[(size_t)m0*16 + li]; }
  int tcol = t & 63, trow = t >> 6;   // GEMM map: n-quad, 8-row group
  int kc = t & 31, mr = t >> 5;       // S map: k-col, 4-row group
  f4 acc[8];
  #pragma unroll
  for (int u=0;u<8;u++){ acc[u].x=0;acc[u].y=0;acc[u].z=0;acc[u].w=0; }
  const f4* Y4 = (const f4*)Y;
  for (int k0=0; k0<NN; k0+=32){
    __syncthreads();
    // stage Zk (swizzled), Y tile (pre-scaled by 1/s), m tile
    #pragma unroll
    for (int u=0;u<2;u++){
      int li=u*256+t; int kk=li>>4, q=li&15;
      zk[(kk<<4) | (q ^ (kk&7))] = Z4[(size_t)k0*16 + li];
    }
    #pragma unroll
    for (int u=0;u<8;u++){
      int li=u*256+t; int kk=li>>6, q=li&63;
      f4 v = Y4[(size_t)(k0+kk)*(F/4) + (n0>>2) + q];
      float sv = sinv[k0+kk];
      v.x*=sv; v.y*=sv; v.z*=sv; v.w*=sv;
      yt[li] = v;
    }
    if (t < 32) mk[t] = mb[k0+t];
    __syncthreads();
    // S tile: each thread 4 rows x 1 col
    float d0=0,d1=0,d2=0,d3=0;
    #pragma unroll
    for (int q=0;q<16;q++){
      f4 b = zk[(kc<<4) | (q ^ (kc&7))];
      f4 a0 = zi[(mr*4+0)*16+q]; d0 += a0.x*b.x+a0.y*b.y+a0.z*b.z+a0.w*b.w;
      f4 a1 = zi[(mr*4+1)*16+q]; d1 += a1.x*b.x+a1.y*b.y+a1.z*b.z+a1.w*b.w;
      f4 a2 = zi[(mr*4+2)*16+q]; d2 += a2.x*b.x+a2.y*b.y+a2.z*b.z+a2.w*b.w;
      f4 a3 = zi[(mr*4+3)*16+q]; d3 += a3.x*b.x+a3.y*b.y+a3.z*b.z+a3.w*b.w;
    }
    float mkv = mk[kc];
    f4 e;
    e.x = __expf(fmaxf(d0,0.f)-mkv);
    e.y = __expf(fmaxf(d1,0.f)-mkv);
    e.z = __expf(fmaxf(d2,0.f)-mkv);
    e.w = __expf(fmaxf(d3,0.f)-mkv);
    *(f4*)&stf[kc*36 + mr*4] = e;
    __syncthreads();
    // GEMM: acc[m][nquad] += S[k][m] * Yt[k][nquad]
    #pragma unroll 8
    for (int kk=0;kk<32;kk++){
      f4 yv = yt[kk*64 + tcol];
      const f4* sp = (const f4*)&stf[kk*36 + trow*8];
      f4 s0 = sp[0], s1 = sp[1];
      acc[0].x += s0.x*yv.x; acc[0].y += s0.x*yv.y; acc[0].z += s0.x*yv.z; acc[0].w += s0.x*yv.w;
      acc[1].x += s0.y*yv.x; acc[1].y += s0.y*yv.y; acc[1].z += s0.y*yv.z; acc[1].w += s0.y*yv.w;
      acc[2].x += s0.z*yv.x; acc[2].y += s0.z*yv.y; acc[2].z += s0.z*yv.z; acc[2].w += s0.z*yv.w;
      acc[3].x += s0.w*yv.x; acc[3].y += s0.w*yv.y; acc[3].z += s0.w*yv.z; acc[3].w += s0.w*yv.w;
      acc[4].x += s1.x*yv.x; acc[4].y += s1.x*yv.y; acc[4].z += s1.x*yv.z; acc[4].w += s1.x*yv.w;
      acc[5].x += s1.y*yv.x; acc[5].y += s1.y*yv.y; acc[5].z += s1.y*yv.z; acc[5].w += s1.y*yv.w;
      acc[6].x += s1.z*yv.x; acc[6].y += s1.z*yv.y; acc[6].z += s1.z*yv.z; acc[6].w += s1.z*yv.w;
      acc[7].x += s1.w*yv.x; acc[7].y += s1.w*yv.y; acc[7].z += s1.w*yv.z; acc[7].w += s1.w*yv.w;
    }
  }
  f4* Tp = (f4*)T;
  #pragma unroll
  for (int u=0;u<8;u++){
    int m = trow*8 + u;
    size_t o = (size_t)(m0+m)*(F/4) + (n0>>2) + tcol;
    f4 old = Tp[o];
    old.x+=acc[u].x; old.y+=acc[u].y; old.z+=acc[u].z; old.w+=acc[u].w;
    Tp[o] = old;
  }
}

// ---------------- head GEMM: Hout[j, b*128+o] = relu(sum_k T[j, b*DIN+k] * W[k,o]) ----------------
template<int DIN, int FIN>
__global__ __launch_bounds__(256) void k_head(const float* __restrict__ T, const float* __restrict__ W,
                                              float* __restrict__ Hout){
  __shared__ float tt[16*DIN];
  int t = threadIdx.x;
  int j0 = blockIdx.x*16, b = blockIdx.y;
  for (int u=t; u<16*DIN; u+=256){
    int jj = u / DIN, k = u % DIN;
    tt[u] = T[(size_t)(j0+jj)*FIN + b*DIN + k];
  }
  __syncthreads();
  int oq = t & 31, jg = t >> 5;
  f4 a0 = {0,0,0,0}, a1 = {0,0,0,0};
  const f4* W4 = (const f4*)W;
  for (int k=0;k<DIN;k++){
    f4 wv = W4[k*32 + oq];
    float t0 = tt[(jg*2+0)*DIN + k];
    float t1 = tt[(jg*2+1)*DIN + k];
    a0.x += t0*wv.x; a0.y += t0*wv.y; a0.z += t0*wv.z; a0.w += t0*wv.w;
    a1.x += t1*wv.x; a1.y += t1*wv.y; a1.z += t1*wv.z; a1.w += t1*wv.w;
  }
  a0.x=fmaxf(a0.x,0.f); a0.y=fmaxf(a0.y,0.f); a0.z=fmaxf(a0.z,0.f); a0.w=fmaxf(a0.w,0.f);
  a1.x=fmaxf(a1.x,0.f); a1.y=fmaxf(a1.y,0.f); a1.z=fmaxf(a1.z,0.f); a1.w=fmaxf(a1.w,0.f);
  f4* H4 = (f4*)Hout;
  H4[(size_t)(j0+jg*2+0)*256 + b*32 + oq] = a0;
  H4[(size_t)(j0+jg*2+1)*256 + b*32 + oq] = a1;
}

// ---------------- final mean over nodes ----------------
__global__ __launch_bounds__(256) void k_reduce(const float* __restrict__ A, float* __restrict__ out){
  __shared__ float accl[1024];
  int t = threadIdx.x;
  for (int u=t; u<1024; u+=256) accl[u]=0.f;
  __syncthreads();
  int j0 = blockIdx.x*128;
  for (int j=j0; j<j0+128; j++){
    for (int u=t; u<1024; u+=256) accl[u] += A[(size_t)j*1024 + u];
  }
  __syncthreads();
  for (int u=t; u<1024; u+=256) atomicAdd(&out[u], accl[u]*(1.f/8192.f));
}

// ---------------- launcher ----------------
extern "C" void kernel_launch(void* const* d_in, const int* in_sizes, int n_in,
                              void* d_out, int out_size, void* d_ws, size_t ws_size,
                              hipStream_t stream){
  const int*   A1i = (const int*)d_in[0];
  const float* A1v = (const float*)d_in[1];
  const int*   A2i = (const int*)d_in[2];
  const float* A2v = (const float*)d_in[3];
  const float* X   = (const float*)d_in[4];
  const float* Z   = (const float*)d_in[5];
  const float* W1  = (const float*)d_in[6];
  const float* W2  = (const float*)d_in[7];
  float* out = (float*)d_out;

  char* w = (char*)d_ws;
  size_t off = 0;
  auto alloc = [&](size_t b)->char* {
    char* p = w + off;
    off += (b + 1023) & ~(size_t)1023;
    return p;
  };
  float* mb    = (float*)alloc(NN*4);
  float* sb    = (float*)alloc(NN*4);
  int*   ptr1  = (int*)  alloc((NN+1)*4);
  int*   ptr2  = (int*)  alloc((NN+1)*4);
  int*   cnt   = (int*)  alloc(NN*4);
  int*   cidx1 = (int*)  alloc(NNZE*4);
  float* cval1 = (float*)alloc(NNZE*4);
  int*   cidx2 = (int*)  alloc(NNZE*4);
  float* cval2 = (float*)alloc(NNZE*4);
  float* XT1   = (float*)alloc((size_t)NN*512*4);
  float* T1    = (float*)alloc((size_t)NN*512*4);   // adjacent to XT1
  float* HT    = (float*)alloc((size_t)NN*1024*4);
  float* TMP   = (float*)alloc((size_t)NN*1024*4);
  float* T2    = XT1;  // overlay XT1+T1 (dead once HT exists); spans 32 MB contiguously
  // total ws need: ~103 MB

  const f4* Z4 = (const f4*)Z;

  // CSR for A1, A2
  hipMemsetAsync(cnt, 0, NN*4, stream);
  k_count<<<NNZE/256, 256, 0, stream>>>(A1i, cnt);
  k_scan<<<1, 1024, 0, stream>>>(cnt, ptr1);
  hipMemcpyAsync(cnt, ptr1, NN*4, hipMemcpyDeviceToDevice, stream);
  k_fill<<<NNZE/256, 256, 0, stream>>>(A1i, A1v, cnt, cidx1, cval1);

  hipMemsetAsync(cnt, 0, NN*4, stream);
  k_count<<<NNZE/256, 256, 0, stream>>>(A2i, cnt);
  k_scan<<<1, 1024, 0, stream>>>(cnt, ptr2);
  hipMemcpyAsync(cnt, ptr2, NN*4, hipMemcpyDeviceToDevice, stream);
  k_fill<<<NNZE/256, 256, 0, stream>>>(A2i, A2v, cnt, cidx2, cval2);

  // Xt (node-major)
  k_transpose<512><<<dim3(NN/32, 512/32), 256, 0, stream>>>(X, XT1);

  // softmax column stats (shared by both layers)
  hipMemsetAsync(mb, 0, NN*4, stream);
  hipMemsetAsync(sb, 0, NN*4, stream);
  k_colmax<<<dim3(64,8), 128, 0, stream>>>(Z4, mb);
  k_colsum<<<dim3(64,8), 128, 0, stream>>>(Z4, mb, sb);
  k_recip<<<NN/256, 256, 0, stream>>>(sb);

  // ---- layer 1 (F=512) ----
  k_spmm<512,1,false><<<NN, 256, 0, stream>>>(ptr1, cidx1, cval1, XT1, TMP);     // A1 X
  k_sub<<<1024, 256, 0, stream>>>((const f4*)TMP, (const f4*)XT1, (f4*)T1, NN*512/4); // T = A1X - X
  k_spmm<512,2,true><<<NN, 256, 0, stream>>>(ptr1, cidx1, cval1, TMP, T1);       // T += 2 A1(A1X)
  k_spmm<512,1,false><<<NN, 256, 0, stream>>>(ptr2, cidx2, cval2, XT1, TMP);     // A2 X
  k_add<<<1024, 256, 0, stream>>>((const f4*)TMP, (f4*)T1, NN*512/4);            // T += A2X
  k_spmm<512,2,true><<<NN, 256, 0, stream>>>(ptr2, cidx2, cval2, TMP, T1);       // T += 2 A2(A2X)
  k_attn<512><<<dim3(NN/32, 2), 256, 0, stream>>>(Z4, XT1, mb, sb, T1);          // T += Az X
  k_head<64,512><<<dim3(NN/16, 8), 256, 0, stream>>>(T1, W1, HT);                // relu(T W1) node-major

  // ---- layer 2 (F=1024), T2 overlays XT1/T1 ----
  k_spmm<1024,1,false><<<NN, 256, 0, stream>>>(ptr1, cidx1, cval1, HT, TMP);
  k_sub<<<2048, 256, 0, stream>>>((const f4*)TMP, (const f4*)HT, (f4*)T2, NN*1024/4);
  k_spmm<1024,2,true><<<NN, 256, 0, stream>>>(ptr1, cidx1, cval1, TMP, T2);
  k_spmm<1024,1,false><<<NN, 256, 0, stream>>>(ptr2, cidx2, cval2, HT, TMP);
  k_add<<<2048, 256, 0, stream>>>((const f4*)TMP, (f4*)T2, NN*1024/4);
  k_spmm<1024,2,true><<<NN, 256, 0, stream>>>(ptr2, cidx2, cval2, TMP, T2);
  k_attn<1024><<<dim3(NN/32, 4), 256, 0, stream>>>(Z4, HT, mb, sb, T2);
  k_head<128,1024><<<dim3(NN/16, 8), 256, 0, stream>>>(T2, W2, TMP);             // OUT2T in TMP

  hipMemsetAsync(out, 0, 1024*4, stream);
  k_reduce<<<64, 256, 0, stream>>>(TMP, out);
}

// Round 2
// 3100.903 us; speedup vs baseline: 1.9629x; 1.9629x over previous
//
#include <hip/hip_runtime.h>

// GWNet on MI355X — round 2: bf16 MFMA fused attention.
// attn = flash-style T += E @ (Y*sinv): S=Z.Z^T via mfma (Zi frags in regs,
// Zk frags direct-global), exp on C-frags, P routed through padded LDS tile,
// PV via mfma with B-frags direct from pre-transposed bf16 Ysb_t.
// Softmax stats computed from bf16-rounded Z for numerator/denominator consistency.

#define NN 8192
#define NNZE 131072

typedef float4 f4;
typedef __attribute__((ext_vector_type(8))) short bf16x8;
typedef __attribute__((ext_vector_type(4))) float f32x4;

__device__ inline short f2b(float x){
  unsigned u = __float_as_uint(x);
  unsigned r = (u + 0x7fffu + ((u >> 16) & 1u)) >> 16;
  return (short)r;
}

// ---------------- CSR build ----------------
__global__ __launch_bounds__(256) void k_count(const int* __restrict__ idx, int* __restrict__ cnt){
  int e = blockIdx.x*256 + threadIdx.x;
  if (e < NNZE) atomicAdd(&cnt[idx[e]], 1);
}

__global__ __launch_bounds__(1024) void k_scan(const int* __restrict__ cnt, int* __restrict__ ptr){
  __shared__ int sums[1024];
  int t = threadIdx.x;
  int loc[8]; int s = 0;
  #pragma unroll
  for (int i=0;i<8;i++){ loc[i]=s; s += cnt[t*8+i]; }
  sums[t]=s; __syncthreads();
  for (int off=1; off<1024; off<<=1){
    int v = (t>=off) ? sums[t-off] : 0;
    __syncthreads();
    sums[t] += v;
    __syncthreads();
  }
  int excl = sums[t]-s;
  #pragma unroll
  for (int i=0;i<8;i++) ptr[t*8+i] = excl + loc[i];
  if (t==1023) ptr[NN] = sums[1023];
}

__global__ __launch_bounds__(256) void k_fill(const int* __restrict__ idx, const float* __restrict__ vals,
                                              int* __restrict__ cur, int* __restrict__ cidx, float* __restrict__ cval){
  int e = blockIdx.x*256 + threadIdx.x;
  if (e < NNZE){
    int r = idx[e], c = idx[NNZE+e];
    int p = atomicAdd(&cur[r], 1);
    cidx[p] = c; cval[p] = vals[e];
  }
}

// ---------------- transpose X (R, NN) -> (NN, R) ----------------
template<int R>
__global__ __launch_bounds__(256) void k_transpose(const float* __restrict__ src, float* __restrict__ dst){
  __shared__ float tile[32][33];
  int tx = threadIdx.x & 31, ty = threadIdx.x >> 5;
  int j0 = blockIdx.x*32, f0 = blockIdx.y*32;
  #pragma unroll
  for (int u=0;u<32;u+=8) tile[ty+u][tx] = src[(size_t)(f0+ty+u)*NN + j0+tx];
  __syncthreads();
  #pragma unroll
  for (int u=0;u<32;u+=8) dst[(size_t)(j0+ty+u)*R + f0+tx] = tile[tx][ty+u];
}

// ---------------- Z prep: bf16 round (Zb) + f32 image of it (Zr) ----------------
__global__ __launch_bounds__(256) void k_zprep(const float* __restrict__ Z, float* __restrict__ Zr, short* __restrict__ Zb){
  int i = blockIdx.x*256 + threadIdx.x;   // NN*64 total
  float v = Z[i];
  short b = f2b(v);
  Zb[i] = b;
  Zr[i] = __uint_as_float(((unsigned)(unsigned short)b) << 16);
}

// ---------------- softmax column stats on Zr: m[j]=max_i relu(zi.zj), s[j]=sum exp(.-m) ----------------
__global__ __launch_bounds__(128) void k_colmax(const f4* __restrict__ Z4, float* __restrict__ mb){
  __shared__ f4 zi[64*16];
  int t = threadIdx.x;
  int j = blockIdx.x*128 + t;
  int i0 = blockIdx.y*1024;
  f4 zj[16];
  #pragma unroll
  for (int q=0;q<16;q++) zj[q] = Z4[(size_t)j*16+q];
  float mx = 0.f;
  for (int it=0; it<1024; it+=64){
    __syncthreads();
    #pragma unroll
    for (int u=0;u<8;u++){ int li=u*128+t; zi[li] = Z4[(size_t)(i0+it)*16 + li]; }
    __syncthreads();
    for (int i=0;i<64;i++){
      float d=0.f;
      #pragma unroll
      for (int q=0;q<16;q++){ f4 a=zi[i*16+q], b=zj[q]; d += a.x*b.x+a.y*b.y+a.z*b.z+a.w*b.w; }
      mx = fmaxf(mx, d);
    }
  }
  atomicMax((int*)(mb+j), __float_as_int(mx));
}

__global__ __launch_bounds__(128) void k_colsum(const f4* __restrict__ Z4, const float* __restrict__ mb, float* __restrict__ sb){
  __shared__ f4 zi[64*16];
  int t = threadIdx.x;
  int j = blockIdx.x*128 + t;
  int i0 = blockIdx.y*1024;
  f4 zj[16];
  #pragma unroll
  for (int q=0;q<16;q++) zj[q] = Z4[(size_t)j*16+q];
  float mj = mb[j];
  float sm = 0.f;
  for (int it=0; it<1024; it+=64){
    __syncthreads();
    #pragma unroll
    for (int u=0;u<8;u++){ int li=u*128+t; zi[li] = Z4[(size_t)(i0+it)*16 + li]; }
    __syncthreads();
    for (int i=0;i<64;i++){
      float d=0.f;
      #pragma unroll
      for (int q=0;q<16;q++){ f4 a=zi[i*16+q], b=zj[q]; d += a.x*b.x+a.y*b.y+a.z*b.z+a.w*b.w; }
      sm += __expf(fmaxf(d,0.f) - mj);
    }
  }
  atomicAdd(sb+j, sm);
}

__global__ __launch_bounds__(256) void k_recip(float* s){
  int i = blockIdx.x*256 + threadIdx.x;
  if (i < NN) s[i] = 1.0f/s[i];
}

// ---------------- CSR spmm ----------------
template<int F, int ALPHA, bool ACC>
__global__ __launch_bounds__(256) void k_spmm(const int* __restrict__ ptr, const int* __restrict__ cidx,
                                              const float* __restrict__ cval, const float* __restrict__ in,
                                              float* __restrict__ out){
  int r = blockIdx.x, t = threadIdx.x;
  int p0 = ptr[r], p1 = ptr[r+1];
  constexpr int PER = F/256;
  float acc[PER];
  #pragma unroll
  for (int u=0;u<PER;u++) acc[u]=0.f;
  for (int p=p0;p<p1;p++){
    int c = cidx[p]; float v = cval[p];
    #pragma unroll
    for (int u=0;u<PER;u++) acc[u] += v * in[(size_t)c*F + u*256 + t];
  }
  #pragma unroll
  for (int u=0;u<PER;u++){
    size_t o = (size_t)r*F + u*256 + t;
    float x = (float)ALPHA * acc[u];
    out[o] = ACC ? (out[o] + x) : x;
  }
}

// ---------------- elementwise ----------------
__global__ __launch_bounds__(256) void k_sub(const f4* __restrict__ a, const f4* __restrict__ b, f4* __restrict__ o, int n4){
  for (int i = blockIdx.x*256 + threadIdx.x; i < n4; i += gridDim.x*256){
    f4 x=a[i], y=b[i]; f4 r;
    r.x=x.x-y.x; r.y=x.y-y.y; r.z=x.z-y.z; r.w=x.w-y.w;
    o[i]=r;
  }
}
__global__ __launch_bounds__(256) void k_add(const f4* __restrict__ a, f4* __restrict__ o, int n4){
  for (int i = blockIdx.x*256 + threadIdx.x; i < n4; i += gridDim.x*256){
    f4 x=a[i], r=o[i];
    r.x+=x.x; r.y+=x.y; r.z+=x.z; r.w+=x.w;
    o[i]=r;
  }
}

// ---------------- Y -> Yt: transpose, scale by sinv[k], cvt bf16. Yt[n][k] ----------------
template<int F>
__global__ __launch_bounds__(256) void k_downt(const float* __restrict__ Y, const float* __restrict__ sinv,
                                               short* __restrict__ Yt){
  __shared__ float tile[32][33];
  int tx = threadIdx.x & 31, ty = threadIdx.x >> 5;
  int k0 = blockIdx.x*32, n0 = blockIdx.y*32;
  #pragma unroll
  for (int u=0;u<32;u+=8) tile[ty+u][tx] = Y[(size_t)(k0+ty+u)*F + n0+tx];
  __syncthreads();
  float sv = sinv[k0+tx];
  #pragma unroll
  for (int u=0;u<32;u+=8) Yt[(size_t)(n0+ty+u)*NN + k0+tx] = f2b(tile[tx][ty+u] * sv);
}

// ---------------- MFMA fused attention: T += P @ Ys ----------------
// BM=128, BN=256, BK=32, 512 threads = 8 waves (2 M x 4 N).
// S = Zb.Zb^T on the fly; P=exp(relu(S)-m) routed via LDS tile [128][40] bf16.
template<int F>
__global__ __launch_bounds__(512, 4) void k_attn_mfma(
    const short* __restrict__ Zb,   // [NN][64] bf16
    const short* __restrict__ Yt,   // [F][NN] bf16, pre-scaled by sinv
    const float* __restrict__ mb,   // [NN] colmax
    float* __restrict__ T)          // [NN][F] f32, accumulated
{
  __shared__ short p_lds[128*40];   // pitch 40 shorts = 80B: 16B-aligned rows, conflict-free
  int t = threadIdx.x;
  int w = t >> 6, l = t & 63;
  int lo = l & 15, g = l >> 4;
  int m0 = blockIdx.x * 128;
  int n0 = blockIdx.y * 256;
  int wm = w >> 2, wn = w & 3;

  const bf16x8* Zb8 = (const bf16x8*)Zb;    // [row*8 + chunk], chunk = 8 feats
  const bf16x8* Yt8 = (const bf16x8*)Yt;

  // Zi A-fragments (block-lifetime): rows m0 + w*16 + lo, feat chunks g*8 and g*8+32
  int zirow = m0 + w*16 + lo;
  bf16x8 ziA0 = Zb8[zirow*8 + g];
  bf16x8 ziA1 = Zb8[zirow*8 + g + 4];

  f32x4 acc[4][4];
  #pragma unroll
  for (int i=0;i<4;i++)
    #pragma unroll
    for (int j=0;j<4;j++) acc[i][j] = (f32x4){0.f,0.f,0.f,0.f};

  for (int k0 = 0; k0 < NN; k0 += 32){
    // ---- S phase: wave w computes S[w*16..w*16+16][0..32) of this tile ----
    int zk0 = (k0 + lo)*8 + g;
    int zk1 = (k0 + 16 + lo)*8 + g;
    bf16x8 b00 = Zb8[zk0], b01 = Zb8[zk0+4];
    bf16x8 b10 = Zb8[zk1], b11 = Zb8[zk1+4];
    f32x4 s0 = (f32x4){0.f,0.f,0.f,0.f};
    f32x4 s1 = (f32x4){0.f,0.f,0.f,0.f};
    s0 = __builtin_amdgcn_mfma_f32_16x16x32_bf16(ziA0, b00, s0, 0,0,0);
    s0 = __builtin_amdgcn_mfma_f32_16x16x32_bf16(ziA1, b01, s0, 0,0,0);
    s1 = __builtin_amdgcn_mfma_f32_16x16x32_bf16(ziA0, b10, s1, 0,0,0);
    s1 = __builtin_amdgcn_mfma_f32_16x16x32_bf16(ziA1, b11, s1, 0,0,0);
    float mv0 = mb[k0 + lo];
    float mv1 = mb[k0 + 16 + lo];
    __syncthreads();            // previous PV reads of p_lds done
    int prow = w*16 + g*4;
    #pragma unroll
    for (int r=0;r<4;r++){
      p_lds[(prow+r)*40 + lo]      = f2b(__expf(fmaxf(s0[r],0.f) - mv0));
      p_lds[(prow+r)*40 + 16 + lo] = f2b(__expf(fmaxf(s1[r],0.f) - mv1));
    }
    __syncthreads();            // P tile visible
    // ---- PV phase: acc += P[wave rows][k-tile] * Ys[k-tile][wave cols] ----
    bf16x8 aP[4];
    #pragma unroll
    for (int mf=0; mf<4; mf++)
      aP[mf] = *(const bf16x8*)&p_lds[(wm*64 + mf*16 + lo)*40 + g*8];
    #pragma unroll
    for (int nf=0; nf<4; nf++){
      bf16x8 bY = Yt8[(size_t)(n0 + wn*64 + nf*16 + lo)*(NN/8) + (k0>>3) + g];
      #pragma unroll
      for (int mf=0; mf<4; mf++)
        acc[mf][nf] = __builtin_amdgcn_mfma_f32_16x16x32_bf16(aP[mf], bY, acc[mf][nf], 0,0,0);
    }
  }
  // ---- epilogue: T += acc ----
  #pragma unroll
  for (int mf=0; mf<4; mf++){
    int row = m0 + wm*64 + mf*16 + g*4;
    #pragma unroll
    for (int nf=0; nf<4; nf++){
      int col = n0 + wn*64 + nf*16 + lo;
      #pragma unroll
      for (int r=0;r<4;r++){
        size_t o = (size_t)(row+r)*F + col;
        T[o] += acc[mf][nf][r];
      }
    }
  }
}

// ---------------- head GEMM ----------------
template<int DIN, int FIN>
__global__ __launch_bounds__(256) void k_head(const float* __restrict__ T, const float* __restrict__ W,
                                              float* __restrict__ Hout){
  __shared__ float tt[16*DIN];
  int t = threadIdx.x;
  int j0 = blockIdx.x*16, b = blockIdx.y;
  for (int u=t; u<16*DIN; u+=256){
    int jj = u / DIN, k = u % DIN;
    tt[u] = T[(size_t)(j0+jj)*FIN + b*DIN + k];
  }
  __syncthreads();
  int oq = t & 31, jg = t >> 5;
  f4 a0 = {0,0,0,0}, a1 = {0,0,0,0};
  const f4* W4 = (const f4*)W;
  for (int k=0;k<DIN;k++){
    f4 wv = W4[k*32 + oq];
    float t0 = tt[(jg*2+0)*DIN + k];
    float t1 = tt[(jg*2+1)*DIN + k];
    a0.x += t0*wv.x; a0.y += t0*wv.y; a0.z += t0*wv.z; a0.w += t0*wv.w;
    a1.x += t1*wv.x; a1.y += t1*wv.y; a1.z += t1*wv.z; a1.w += t1*wv.w;
  }
  a0.x=fmaxf(a0.x,0.f); a0.y=fmaxf(a0.y,0.f); a0.z=fmaxf(a0.z,0.f); a0.w=fmaxf(a0.w,0.f);
  a1.x=fmaxf(a1.x,0.f); a1.y=fmaxf(a1.y,0.f); a1.z=fmaxf(a1.z,0.f); a1.w=fmaxf(a1.w,0.f);
  f4* H4 = (f4*)Hout;
  H4[(size_t)(j0+jg*2+0)*256 + b*32 + oq] = a0;
  H4[(size_t)(j0+jg*2+1)*256 + b*32 + oq] = a1;
}

// ---------------- final mean over nodes ----------------
__global__ __launch_bounds__(256) void k_reduce(const float* __restrict__ A, float* __restrict__ out){
  __shared__ float accl[1024];
  int t = threadIdx.x;
  for (int u=t; u<1024; u+=256) accl[u]=0.f;
  __syncthreads();
  int j0 = blockIdx.x*128;
  for (int j=j0; j<j0+128; j++){
    for (int u=t; u<1024; u+=256) accl[u] += A[(size_t)j*1024 + u];
  }
  __syncthreads();
  for (int u=t; u<1024; u+=256) atomicAdd(&out[u], accl[u]*(1.f/8192.f));
}

// ---------------- launcher ----------------
extern "C" void kernel_launch(void* const* d_in, const int* in_sizes, int n_in,
                              void* d_out, int out_size, void* d_ws, size_t ws_size,
                              hipStream_t stream){
  const int*   A1i = (const int*)d_in[0];
  const float* A1v = (const float*)d_in[1];
  const int*   A2i = (const int*)d_in[2];
  const float* A2v = (const float*)d_in[3];
  const float* X   = (const float*)d_in[4];
  const float* Z   = (const float*)d_in[5];
  const float* W1  = (const float*)d_in[6];
  const float* W2  = (const float*)d_in[7];
  float* out = (float*)d_out;

  char* w = (char*)d_ws;
  size_t off = 0;
  auto alloc = [&](size_t b)->char* {
    char* p = w + off;
    off += (b + 1023) & ~(size_t)1023;
    return p;
  };
  float* mb    = (float*)alloc(NN*4);
  float* sb    = (float*)alloc(NN*4);
  int*   ptr1  = (int*)  alloc((NN+1)*4);
  int*   ptr2  = (int*)  alloc((NN+1)*4);
  int*   cnt   = (int*)  alloc(NN*4);
  int*   cidx1 = (int*)  alloc(NNZE*4);
  float* cval1 = (float*)alloc(NNZE*4);
  int*   cidx2 = (int*)  alloc(NNZE*4);
  float* cval2 = (float*)alloc(NNZE*4);
  float* Zr    = (float*)alloc((size_t)NN*64*4);     // bf16-rounded Z as f32
  short* Zbf   = (short*)alloc((size_t)NN*64*2);     // Z in bf16
  float* XT1   = (float*)alloc((size_t)NN*512*4);
  float* T1    = (float*)alloc((size_t)NN*512*4);    // adjacent to XT1
  float* HT    = (float*)alloc((size_t)NN*1024*4);
  float* TMP   = (float*)alloc((size_t)NN*1024*4);
  float* T2    = XT1;          // layer-2 T overlays XT1+T1 (32 MB contiguous)
  short* Ysbt  = (short*)TMP;  // Yt bf16 overlays TMP (dead at attn time)

  // CSR for A1, A2
  hipMemsetAsync(cnt, 0, NN*4, stream);
  k_count<<<NNZE/256, 256, 0, stream>>>(A1i, cnt);
  k_scan<<<1, 1024, 0, stream>>>(cnt, ptr1);
  hipMemcpyAsync(cnt, ptr1, NN*4, hipMemcpyDeviceToDevice, stream);
  k_fill<<<NNZE/256, 256, 0, stream>>>(A1i, A1v, cnt, cidx1, cval1);

  hipMemsetAsync(cnt, 0, NN*4, stream);
  k_count<<<NNZE/256, 256, 0, stream>>>(A2i, cnt);
  k_scan<<<1, 1024, 0, stream>>>(cnt, ptr2);
  hipMemcpyAsync(cnt, ptr2, NN*4, hipMemcpyDeviceToDevice, stream);
  k_fill<<<NNZE/256, 256, 0, stream>>>(A2i, A2v, cnt, cidx2, cval2);

  // Xt (node-major)
  k_transpose<512><<<dim3(NN/32, 512/32), 256, 0, stream>>>(X, XT1);

  // Z prep + softmax column stats (on bf16-rounded Z, shared by both layers)
  k_zprep<<<NN*64/256, 256, 0, stream>>>(Z, Zr, Zbf);
  hipMemsetAsync(mb, 0, NN*4, stream);
  hipMemsetAsync(sb, 0, NN*4, stream);
  k_colmax<<<dim3(64,8), 128, 0, stream>>>((const f4*)Zr, mb);
  k_colsum<<<dim3(64,8), 128, 0, stream>>>((const f4*)Zr, mb, sb);
  k_recip<<<NN/256, 256, 0, stream>>>(sb);

  // ---- layer 1 (F=512) ----
  k_spmm<512,1,false><<<NN, 256, 0, stream>>>(ptr1, cidx1, cval1, XT1, TMP);
  k_sub<<<1024, 256, 0, stream>>>((const f4*)TMP, (const f4*)XT1, (f4*)T1, NN*512/4);
  k_spmm<512,2,true><<<NN, 256, 0, stream>>>(ptr1, cidx1, cval1, TMP, T1);
  k_spmm<512,1,false><<<NN, 256, 0, stream>>>(ptr2, cidx2, cval2, XT1, TMP);
  k_add<<<1024, 256, 0, stream>>>((const f4*)TMP, (f4*)T1, NN*512/4);
  k_spmm<512,2,true><<<NN, 256, 0, stream>>>(ptr2, cidx2, cval2, TMP, T1);
  k_downt<512><<<dim3(NN/32, 512/32), 256, 0, stream>>>(XT1, sb, Ysbt);   // TMP now = Yt bf16
  k_attn_mfma<512><<<dim3(NN/128, 2), 512, 0, stream>>>(Zbf, Ysbt, mb, T1);
  k_head<64,512><<<dim3(NN/16, 8), 256, 0, stream>>>(T1, W1, HT);

  // ---- layer 2 (F=1024), T2 overlays XT1/T1 ----
  k_spmm<1024,1,false><<<NN, 256, 0, stream>>>(ptr1, cidx1, cval1, HT, TMP);
  k_sub<<<2048, 256, 0, stream>>>((const f4*)TMP, (const f4*)HT, (f4*)T2, NN*1024/4);
  k_spmm<1024,2,true><<<NN, 256, 0, stream>>>(ptr1, cidx1, cval1, TMP, T2);
  k_spmm<1024,1,false><<<NN, 256, 0, stream>>>(ptr2, cidx2, cval2, HT, TMP);
  k_add<<<2048, 256, 0, stream>>>((const f4*)TMP, (f4*)T2, NN*1024/4);
  k_spmm<1024,2,true><<<NN, 256, 0, stream>>>(ptr2, cidx2, cval2, TMP, T2);
  k_downt<1024><<<dim3(NN/32, 1024/32), 256, 0, stream>>>(HT, sb, Ysbt);  // TMP = Yt bf16 (16 MB)
  k_attn_mfma<1024><<<dim3(NN/128, 4), 512, 0, stream>>>(Zbf, Ysbt, mb, T2);
  k_head<128,1024><<<dim3(NN/16, 8), 256, 0, stream>>>(T2, W2, HT);       // out2 (node-major) into HT

  hipMemsetAsync(out, 0, 1024*4, stream);
  k_reduce<<<64, 256, 0, stream>>>(HT, out);
}

// Round 3
// 1171.741 us; speedup vs baseline: 5.1947x; 2.6464x over previous
//
#include <hip/hip_runtime.h>

// GWNet on MI355X — round 3: latency-fixed MFMA attention.
// - k_attn2: BM=128/BN=256/BK=32, 8 waves; Zk+Yt double-buffered in LDS via
//   global_load_lds(16B) with XOR-swizzle (inverse-swizzled global source,
//   swizzled ds_read — conflict-free b128); K-split grid.z for occupancy,
//   partials merged by vector-add (no atomics).
// - softmax stats: fixed shift C=48 (no column max needed for relu'd scores),
//   single MFMA column-sum kernel on bf16 Z — dots bitwise match attn S-phase.

#define NN 8192
#define NNZE 131072
#define CSHIFT 48.0f

typedef float4 f4;
typedef __attribute__((ext_vector_type(8))) short bf16x8;
typedef __attribute__((ext_vector_type(4))) float f32x4;

typedef __attribute__((address_space(3))) short lds_short;
typedef __attribute__((address_space(1))) const short glb_short;

__device__ inline short f2b(float x){
  unsigned u = __float_as_uint(x);
  unsigned r = (u + 0x7fffu + ((u >> 16) & 1u)) >> 16;
  return (short)r;
}

// ---------------- CSR build ----------------
__global__ __launch_bounds__(256) void k_count(const int* __restrict__ idx, int* __restrict__ cnt){
  int e = blockIdx.x*256 + threadIdx.x;
  if (e < NNZE) atomicAdd(&cnt[idx[e]], 1);
}

__global__ __launch_bounds__(1024) void k_scan(const int* __restrict__ cnt, int* __restrict__ ptr){
  __shared__ int sums[1024];
  int t = threadIdx.x;
  int loc[8]; int s = 0;
  #pragma unroll
  for (int i=0;i<8;i++){ loc[i]=s; s += cnt[t*8+i]; }
  sums[t]=s; __syncthreads();
  for (int off=1; off<1024; off<<=1){
    int v = (t>=off) ? sums[t-off] : 0;
    __syncthreads();
    sums[t] += v;
    __syncthreads();
  }
  int excl = sums[t]-s;
  #pragma unroll
  for (int i=0;i<8;i++) ptr[t*8+i] = excl + loc[i];
  if (t==1023) ptr[NN] = sums[1023];
}

__global__ __launch_bounds__(256) void k_fill(const int* __restrict__ idx, const float* __restrict__ vals,
                                              int* __restrict__ cur, int* __restrict__ cidx, float* __restrict__ cval){
  int e = blockIdx.x*256 + threadIdx.x;
  if (e < NNZE){
    int r = idx[e], c = idx[NNZE+e];
    int p = atomicAdd(&cur[r], 1);
    cidx[p] = c; cval[p] = vals[e];
  }
}

// ---------------- transpose X (R, NN) -> (NN, R) ----------------
template<int R>
__global__ __launch_bounds__(256) void k_transpose(const float* __restrict__ src, float* __restrict__ dst){
  __shared__ float tile[32][33];
  int tx = threadIdx.x & 31, ty = threadIdx.x >> 5;
  int j0 = blockIdx.x*32, f0 = blockIdx.y*32;
  #pragma unroll
  for (int u=0;u<32;u+=8) tile[ty+u][tx] = src[(size_t)(f0+ty+u)*NN + j0+tx];
  __syncthreads();
  #pragma unroll
  for (int u=0;u<32;u+=8) dst[(size_t)(j0+ty+u)*R + f0+tx] = tile[tx][ty+u];
}

// ---------------- Z -> bf16 ----------------
__global__ __launch_bounds__(256) void k_zb(const float* __restrict__ Z, short* __restrict__ Zb){
  int i = blockIdx.x*256 + threadIdx.x;   // NN*64 total
  Zb[i] = f2b(Z[i]);
}

// ---------------- column sums via MFMA: sb[j] = sum_i exp(relu(zi.zj) - C) ----------------
__global__ __launch_bounds__(512) void k_colsum_mfma(const short* __restrict__ Zb, float* __restrict__ sb){
  int t = threadIdx.x;
  int w = t >> 6, l = t & 63;
  int lo = l & 15, g = l >> 4;
  int j = blockIdx.x*128 + w*16 + lo;
  const bf16x8* Zb8 = (const bf16x8*)Zb;
  bf16x8 bj0 = Zb8[j*8 + g];
  bf16x8 bj1 = Zb8[j*8 + g + 4];
  int i0 = blockIdx.y * (NN/8);
  float sum = 0.f;
  for (int i = i0; i < i0 + NN/8; i += 16){
    bf16x8 a0 = Zb8[(size_t)(i+lo)*8 + g];
    bf16x8 a1 = Zb8[(size_t)(i+lo)*8 + g + 4];
    f32x4 s = (f32x4){0.f,0.f,0.f,0.f};
    s = __builtin_amdgcn_mfma_f32_16x16x32_bf16(a0, bj0, s, 0,0,0);
    s = __builtin_amdgcn_mfma_f32_16x16x32_bf16(a1, bj1, s, 0,0,0);
    #pragma unroll
    for (int r=0;r<4;r++) sum += __expf(fmaxf(s[r],0.f) - CSHIFT);
  }
  sum += __shfl_xor(sum, 16);
  sum += __shfl_xor(sum, 32);
  if (g == 0) atomicAdd(sb + j, sum);
}

__global__ __launch_bounds__(256) void k_recip(float* s){
  int i = blockIdx.x*256 + threadIdx.x;
  if (i < NN) s[i] = 1.0f/s[i];
}

// ---------------- CSR spmm ----------------
template<int F, int ALPHA, bool ACC>
__global__ __launch_bounds__(256) void k_spmm(const int* __restrict__ ptr, const int* __restrict__ cidx,
                                              const float* __restrict__ cval, const float* __restrict__ in,
                                              float* __restrict__ out){
  int r = blockIdx.x, t = threadIdx.x;
  int p0 = ptr[r], p1 = ptr[r+1];
  constexpr int PER = F/256;
  float acc[PER];
  #pragma unroll
  for (int u=0;u<PER;u++) acc[u]=0.f;
  for (int p=p0;p<p1;p++){
    int c = cidx[p]; float v = cval[p];
    #pragma unroll
    for (int u=0;u<PER;u++) acc[u] += v * in[(size_t)c*F + u*256 + t];
  }
  #pragma unroll
  for (int u=0;u<PER;u++){
    size_t o = (size_t)r*F + u*256 + t;
    float x = (float)ALPHA * acc[u];
    out[o] = ACC ? (out[o] + x) : x;
  }
}

// ---------------- elementwise ----------------
__global__ __launch_bounds__(256) void k_sub(const f4* __restrict__ a, const f4* __restrict__ b, f4* __restrict__ o, int n4){
  for (int i = blockIdx.x*256 + threadIdx.x; i < n4; i += gridDim.x*256){
    f4 x=a[i], y=b[i]; f4 r;
    r.x=x.x-y.x; r.y=x.y-y.y; r.z=x.z-y.z; r.w=x.w-y.w;
    o[i]=r;
  }
}
__global__ __launch_bounds__(256) void k_add(const f4* __restrict__ a, f4* __restrict__ o, int n4){
  for (int i = blockIdx.x*256 + threadIdx.x; i < n4; i += gridDim.x*256){
    f4 x=a[i], r=o[i];
    r.x+=x.x; r.y+=x.y; r.z+=x.z; r.w+=x.w;
    o[i]=r;
  }
}
__global__ __launch_bounds__(256) void k_acc1(const f4* __restrict__ a, f4* __restrict__ o, int n4){
  for (int i = blockIdx.x*256 + threadIdx.x; i < n4; i += gridDim.x*256){
    f4 x=a[i], r=o[i];
    r.x+=x.x; r.y+=x.y; r.z+=x.z; r.w+=x.w;
    o[i]=r;
  }
}
__global__ __launch_bounds__(256) void k_acc3(const f4* __restrict__ a, const f4* __restrict__ b,
                                              const f4* __restrict__ c, f4* __restrict__ o, int n4){
  for (int i = blockIdx.x*256 + threadIdx.x; i < n4; i += gridDim.x*256){
    f4 x=a[i], y=b[i], z=c[i], r=o[i];
    r.x+=x.x+y.x+z.x; r.y+=x.y+y.y+z.y; r.z+=x.z+y.z+z.z; r.w+=x.w+y.w+z.w;
    o[i]=r;
  }
}

// ---------------- Y -> Yt: transpose, scale by sinv[k], cvt bf16. Yt[n][k] ----------------
template<int F>
__global__ __launch_bounds__(256) void k_downt(const float* __restrict__ Y, const float* __restrict__ sinv,
                                               short* __restrict__ Yt){
  __shared__ float tile[32][33];
  int tx = threadIdx.x & 31, ty = threadIdx.x >> 5;
  int k0 = blockIdx.x*32, n0 = blockIdx.y*32;
  #pragma unroll
  for (int u=0;u<32;u+=8) tile[ty+u][tx] = Y[(size_t)(k0+ty+u)*F + n0+tx];
  __syncthreads();
  float sv = sinv[k0+tx];
  #pragma unroll
  for (int u=0;u<32;u+=8) Yt[(size_t)(n0+ty+u)*NN + k0+tx] = f2b(tile[tx][ty+u] * sv);
}

// ---------------- MFMA fused attention: out += / = P @ Ys ----------------
// BM=128, BN=256, BK=32, 512 threads = 8 waves (2M x 4N). K-split via blockIdx.z.
// Zk tile and Yt tile staged in LDS (double-buffered, global_load_lds 16B,
// XOR-swizzled source so swizzled ds_read_b128 is bank-conflict-free).
template<int F>
__global__ __launch_bounds__(512, 4) void k_attn2(
    const short* __restrict__ Zb,   // [NN][64] bf16
    const short* __restrict__ Ytg,  // [F][NN]  bf16, pre-scaled by sinv
    float* __restrict__ T0,         // kz==0 accumulates here
    float* __restrict__ P1, float* __restrict__ P2, float* __restrict__ P3,  // kz>=1 stores
    int ksize)
{
  __shared__ __align__(16) short zk[2][32*64];     // 8 KB
  __shared__ __align__(16) short yt[2][256*32];    // 32 KB
  __shared__ __align__(16) short p_lds[128*40];    // 10 KB
  int t = threadIdx.x;
  int w = t >> 6, l = t & 63;
  int lo = l & 15, g = l >> 4;
  int m0 = blockIdx.x * 128;
  int n0 = blockIdx.y * 256;
  int kz = blockIdx.z;
  int kbeg = kz * ksize, kend = kbeg + ksize;
  int wm = w >> 2, wn = w & 3;

  const bf16x8* Zb8 = (const bf16x8*)Zb;
  int zirow = m0 + w*16 + lo;
  bf16x8 ziA0 = Zb8[(size_t)zirow*8 + g];
  bf16x8 ziA1 = Zb8[(size_t)zirow*8 + g + 4];

  f32x4 acc[4][4];
  #pragma unroll
  for (int i=0;i<4;i++)
    #pragma unroll
    for (int j=0;j<4;j++) acc[i][j] = (f32x4){0.f,0.f,0.f,0.f};

  auto STAGE = [&](int b, int kk){
    if (t < 256){
      int r = t >> 3, c = t & 7;              // Zk: 32 rows x 8 chunks(16B)
      const short* src = Zb + (((size_t)(kk + r)) << 6) + ((c ^ (r & 7)) << 3);
      __builtin_amdgcn_global_load_lds((glb_short*)src, (lds_short*)&zk[b][t*8], 16, 0, 0);
    }
    #pragma unroll
    for (int p=0;p<2;p++){
      int cc = p*512 + t;                     // Yt: 256 rows x 4 chunks(16B)
      int r = cc >> 2, c = cc & 3;
      const short* src = Ytg + (size_t)(n0 + r)*NN + kk + ((c ^ (r & 3)) << 3);
      __builtin_amdgcn_global_load_lds((glb_short*)src, (lds_short*)&yt[b][cc*8], 16, 0, 0);
    }
  };

  STAGE(0, kbeg);
  __syncthreads();

  int cur = 0;
  for (int k0 = kbeg; k0 < kend; k0 += 32){
    // ---- S phase: wave w computes S[w*16..+16][0..32) from zk[cur] ----
    int xa = g ^ (lo & 7), xb = (g + 4) ^ (lo & 7);
    bf16x8 b00 = *(const bf16x8*)&zk[cur][(lo*8 + xa)*8];
    bf16x8 b01 = *(const bf16x8*)&zk[cur][(lo*8 + xb)*8];
    bf16x8 b10 = *(const bf16x8*)&zk[cur][((16+lo)*8 + xa)*8];
    bf16x8 b11 = *(const bf16x8*)&zk[cur][((16+lo)*8 + xb)*8];
    f32x4 s0 = (f32x4){0.f,0.f,0.f,0.f};
    f32x4 s1 = (f32x4){0.f,0.f,0.f,0.f};
    s0 = __builtin_amdgcn_mfma_f32_16x16x32_bf16(ziA0, b00, s0, 0,0,0);
    s0 = __builtin_amdgcn_mfma_f32_16x16x32_bf16(ziA1, b01, s0, 0,0,0);
    s1 = __builtin_amdgcn_mfma_f32_16x16x32_bf16(ziA0, b10, s1, 0,0,0);
    s1 = __builtin_amdgcn_mfma_f32_16x16x32_bf16(ziA1, b11, s1, 0,0,0);
    short e0[4], e1[4];
    #pragma unroll
    for (int r=0;r<4;r++){
      e0[r] = f2b(__expf(fmaxf(s0[r],0.f) - CSHIFT));
      e1[r] = f2b(__expf(fmaxf(s1[r],0.f) - CSHIFT));
    }
    __syncthreads();                 // B1: all reads of both buffers retired
    if (k0 + 32 < kend) STAGE(cur ^ 1, k0 + 32);
    int prow = w*16 + g*4;
    #pragma unroll
    for (int r=0;r<4;r++){
      p_lds[(prow+r)*40 + lo]      = e0[r];
      p_lds[(prow+r)*40 + 16 + lo] = e1[r];
    }
    __syncthreads();                 // B2: stage drained, P visible
    // ---- PV phase ----
    bf16x8 aP[4];
    #pragma unroll
    for (int mf=0; mf<4; mf++)
      aP[mf] = *(const bf16x8*)&p_lds[(wm*64 + mf*16 + lo)*40 + g*8];
    #pragma unroll
    for (int nf=0; nf<4; nf++){
      int nl = wn*64 + nf*16 + lo;
      bf16x8 bY = *(const bf16x8*)&yt[cur][(nl*4 + (g ^ (nl & 3)))*8];
      #pragma unroll
      for (int mf=0; mf<4; mf++)
        acc[mf][nf] = __builtin_amdgcn_mfma_f32_16x16x32_bf16(aP[mf], bY, acc[mf][nf], 0,0,0);
    }
    cur ^= 1;
  }
  // ---- epilogue ----
  float* outp = (kz==0) ? T0 : (kz==1 ? P1 : (kz==2 ? P2 : P3));
  #pragma unroll
  for (int mf=0; mf<4; mf++){
    int row = m0 + wm*64 + mf*16 + g*4;
    #pragma unroll
    for (int nf=0; nf<4; nf++){
      int col = n0 + wn*64 + nf*16 + lo;
      #pragma unroll
      for (int r=0;r<4;r++){
        size_t o = (size_t)(row+r)*F + col;
        if (kz==0) outp[o] += acc[mf][nf][r];
        else       outp[o]  = acc[mf][nf][r];
      }
    }
  }
}

// ---------------- head GEMM ----------------
template<int DIN, int FIN>
__global__ __launch_bounds__(256) void k_head(const float* __restrict__ T, const float* __restrict__ W,
                                              float* __restrict__ Hout){
  __shared__ float tt[16*DIN];
  int t = threadIdx.x;
  int j0 = blockIdx.x*16, b = blockIdx.y;
  for (int u=t; u<16*DIN; u+=256){
    int jj = u / DIN, k = u % DIN;
    tt[u] = T[(size_t)(j0+jj)*FIN + b*DIN + k];
  }
  __syncthreads();
  int oq = t & 31, jg = t >> 5;
  f4 a0 = {0,0,0,0}, a1 = {0,0,0,0};
  const f4* W4 = (const f4*)W;
  for (int k=0;k<DIN;k++){
    f4 wv = W4[k*32 + oq];
    float t0 = tt[(jg*2+0)*DIN + k];
    float t1 = tt[(jg*2+1)*DIN + k];
    a0.x += t0*wv.x; a0.y += t0*wv.y; a0.z += t0*wv.z; a0.w += t0*wv.w;
    a1.x += t1*wv.x; a1.y += t1*wv.y; a1.z += t1*wv.z; a1.w += t1*wv.w;
  }
  a0.x=fmaxf(a0.x,0.f); a0.y=fmaxf(a0.y,0.f); a0.z=fmaxf(a0.z,0.f); a0.w=fmaxf(a0.w,0.f);
  a1.x=fmaxf(a1.x,0.f); a1.y=fmaxf(a1.y,0.f); a1.z=fmaxf(a1.z,0.f); a1.w=fmaxf(a1.w,0.f);
  f4* H4 = (f4*)Hout;
  H4[(size_t)(j0+jg*2+0)*256 + b*32 + oq] = a0;
  H4[(size_t)(j0+jg*2+1)*256 + b*32 + oq] = a1;
}

// ---------------- final mean over nodes ----------------
__global__ __launch_bounds__(256) void k_reduce(const float* __restrict__ A, float* __restrict__ out){
  __shared__ float accl[1024];
  int t = threadIdx.x;
  for (int u=t; u<1024; u+=256) accl[u]=0.f;
  __syncthreads();
  int j0 = blockIdx.x*128;
  for (int j=j0; j<j0+128; j++){
    for (int u=t; u<1024; u+=256) accl[u] += A[(size_t)j*1024 + u];
  }
  __syncthreads();
  for (int u=t; u<1024; u+=256) atomicAdd(&out[u], accl[u]*(1.f/8192.f));
}

// ---------------- launcher ----------------
extern "C" void kernel_launch(void* const* d_in, const int* in_sizes, int n_in,
                              void* d_out, int out_size, void* d_ws, size_t ws_size,
                              hipStream_t stream){
  const int*   A1i = (const int*)d_in[0];
  const float* A1v = (const float*)d_in[1];
  const int*   A2i = (const int*)d_in[2];
  const float* A2v = (const float*)d_in[3];
  const float* X   = (const float*)d_in[4];
  const float* Z   = (const float*)d_in[5];
  const float* W1  = (const float*)d_in[6];
  const float* W2  = (const float*)d_in[7];
  float* out = (float*)d_out;

  char* w = (char*)d_ws;
  size_t off = 0;
  auto alloc = [&](size_t b)->char* {
    char* p = w + off;
    off += (b + 1023) & ~(size_t)1023;
    return p;
  };
  float* sb    = (float*)alloc(NN*4);
  int*   ptr1  = (int*)  alloc((NN+1)*4);
  int*   ptr2  = (int*)  alloc((NN+1)*4);
  int*   cnt   = (int*)  alloc(NN*4);
  int*   cidx1 = (int*)  alloc(NNZE*4);
  float* cval1 = (float*)alloc(NNZE*4);
  int*   cidx2 = (int*)  alloc(NNZE*4);
  float* cval2 = (float*)alloc(NNZE*4);
  short* Zbf   = (short*)alloc((size_t)NN*64*2);     // Z in bf16
  float* XT1   = (float*)alloc((size_t)NN*512*4);
  float* T1    = (float*)alloc((size_t)NN*512*4);    // adjacent to XT1
  float* HT    = (float*)alloc((size_t)NN*1024*4);
  float* TMP   = (float*)alloc((size_t)NN*1024*4);
  float* T2    = XT1;           // layer-2 T overlays XT1+T1 (32 MB contiguous)
  short* Ysbt  = (short*)TMP;   // Yt bf16 at TMP base (8/16 MB)
  // K-split partial buffers (dead regions during each attn):
  float* P1a = HT;                         // layer1: HT is dead until k_head
  float* P1b = HT + (size_t)NN*512;
  float* P1c = (float*)((char*)TMP + (size_t)NN*512*2);  // after 8MB Yt
  float* P2a = HT;                         // layer2: HT dead after k_downt

  // CSR for A1, A2
  hipMemsetAsync(cnt, 0, NN*4, stream);
  k_count<<<NNZE/256, 256, 0, stream>>>(A1i, cnt);
  k_scan<<<1, 1024, 0, stream>>>(cnt, ptr1);
  hipMemcpyAsync(cnt, ptr1, NN*4, hipMemcpyDeviceToDevice, stream);
  k_fill<<<NNZE/256, 256, 0, stream>>>(A1i, A1v, cnt, cidx1, cval1);

  hipMemsetAsync(cnt, 0, NN*4, stream);
  k_count<<<NNZE/256, 256, 0, stream>>>(A2i, cnt);
  k_scan<<<1, 1024, 0, stream>>>(cnt, ptr2);
  hipMemcpyAsync(cnt, ptr2, NN*4, hipMemcpyDeviceToDevice, stream);
  k_fill<<<NNZE/256, 256, 0, stream>>>(A2i, A2v, cnt, cidx2, cval2);

  // Xt (node-major)
  k_transpose<512><<<dim3(NN/32, 512/32), 256, 0, stream>>>(X, XT1);

  // Z -> bf16, column sums (MFMA), reciprocal
  k_zb<<<NN*64/256, 256, 0, stream>>>(Z, Zbf);
  hipMemsetAsync(sb, 0, NN*4, stream);
  k_colsum_mfma<<<dim3(NN/128, 8), 512, 0, stream>>>(Zbf, sb);
  k_recip<<<NN/256, 256, 0, stream>>>(sb);

  // ---- layer 1 (F=512) ----
  k_spmm<512,1,false><<<NN, 256, 0, stream>>>(ptr1, cidx1, cval1, XT1, TMP);
  k_sub<<<1024, 256, 0, stream>>>((const f4*)TMP, (const f4*)XT1, (f4*)T1, NN*512/4);
  k_spmm<512,2,true><<<NN, 256, 0, stream>>>(ptr1, cidx1, cval1, TMP, T1);
  k_spmm<512,1,false><<<NN, 256, 0, stream>>>(ptr2, cidx2, cval2, XT1, TMP);
  k_add<<<1024, 256, 0, stream>>>((const f4*)TMP, (f4*)T1, NN*512/4);
  k_spmm<512,2,true><<<NN, 256, 0, stream>>>(ptr2, cidx2, cval2, TMP, T1);
  k_downt<512><<<dim3(NN/32, 512/32), 256, 0, stream>>>(XT1, sb, Ysbt);   // TMP[0..8MB) = Yt
  k_attn2<512><<<dim3(NN/128, 2, 4), 512, 0, stream>>>(Zbf, Ysbt, T1, P1a, P1b, P1c, NN/4);
  k_acc3<<<1024, 256, 0, stream>>>((const f4*)P1a, (const f4*)P1b, (const f4*)P1c, (f4*)T1, NN*512/4);
  k_head<64,512><<<dim3(NN/16, 8), 256, 0, stream>>>(T1, W1, HT);

  // ---- layer 2 (F=1024), T2 overlays XT1/T1 ----
  k_spmm<1024,1,false><<<NN, 256, 0, stream>>>(ptr1, cidx1, cval1, HT, TMP);
  k_sub<<<2048, 256, 0, stream>>>((const f4*)TMP, (const f4*)HT, (f4*)T2, NN*1024/4);
  k_spmm<1024,2,true><<<NN, 256, 0, stream>>>(ptr1, cidx1, cval1, TMP, T2);
  k_spmm<1024,1,false><<<NN, 256, 0, stream>>>(ptr2, cidx2, cval2, HT, TMP);
  k_add<<<2048, 256, 0, stream>>>((const f4*)TMP, (f4*)T2, NN*1024/4);
  k_spmm<1024,2,true><<<NN, 256, 0, stream>>>(ptr2, cidx2, cval2, TMP, T2);
  k_downt<1024><<<dim3(NN/32, 1024/32), 256, 0, stream>>>(HT, sb, Ysbt);  // TMP[0..16MB) = Yt; HT now dead
  k_attn2<1024><<<dim3(NN/128, 4, 2), 512, 0, stream>>>(Zbf, Ysbt, T2, P2a, P2a, P2a, NN/2);
  k_acc1<<<2048, 256, 0, stream>>>((const f4*)P2a, (f4*)T2, NN*1024/4);
  k_head<128,1024><<<dim3(NN/16, 8), 256, 0, stream>>>(T2, W2, HT);

  hipMemsetAsync(out, 0, 1024*4, stream);
  k_reduce<<<64, 256, 0, stream>>>(HT, out);
}